// Round 4
// baseline (282.214 us; speedup 1.0000x reference)
//
#include <hip/hip_runtime.h>
#include <hip/hip_bf16.h>

// Capsule EM routing, fused, votes recomputed in registers each pass.
// B=32, H=W=8, I=32 -> N=2048 per b, O=64, P=16, routings=3.
//
// Round-4: wave = (b, fixed i, 8 sites), lane = o. w[i][o][:] is loaded ONCE
// per wave into 16 registers; the site loop touches only LDS broadcasts +
// shuffles + VALU (no global-load latency chain in the loop). Block = 4
// waves = 4 consecutive i's sharing a pose tile. Grid (64,32) = 2048 blocks
// = 8 blocks/CU. Intermediate stats are recomputed per-wave as a prologue of
// the next accum pass (deterministic), cutting launches to 5.

#define NB 32
#define NN 2048
#define NO 64
#define NP 16
#define EPSF 1e-7f

// accum layout per b: [slot][o], slots 0..15 = sum rr'*v, 16..31 = sum
// rr'*v^2, 32 = rps.
#define ACC_SLOTS 33
#define ACC_PER_B (ACC_SLOTS * NO)
#define ACC_TOTAL (NB * ACC_PER_B)

template <bool FIRST>
__global__ __launch_bounds__(256, 4) void accum_kernel(
    const float* __restrict__ pose,      // [B][N][16], N = site*32 + i
    const float* __restrict__ act,       // [B][N]
    const float* __restrict__ wmat,      // [I=32][O=64][16]
    const float* __restrict__ accumPrev, // [B][33][64] prev pass (null if FIRST)
    const float* __restrict__ beta_v,    // [64]
    const float* __restrict__ beta_a,    // [64]
    float inv_temp,
    float* __restrict__ accumOut)        // [B][33][64] (pre-zeroed)
{
    __shared__ float pose_s[8 * 4 * 16];  // 8 sites x 4 i x 16 = 2 KB
    __shared__ float act_s[8 * 4];

    const int b   = blockIdx.y;
    const int gx  = blockIdx.x;      // 0..63
    const int sg  = gx >> 3;         // site-group 0..7 (8 sites each)
    const int iq  = gx & 7;          // i-quad 0..7 (4 i's each)
    const int tid = threadIdx.x;
    const int wv  = tid >> 6;        // wave -> i within quad
    const int o   = tid & 63;        // lane -> output capsule

    // ---- cooperative tile load: 8 sites x 4 i x 16 floats (+ act) ----
    if (tid < 128) {
        const int srow = tid >> 4, r = tid & 15;
        const int icol = r >> 2, wd = r & 3;
        const size_t gidx = ((size_t)b * NN + (sg * 8 + srow) * 32 + iq * 4 + icol) * 4 + wd;
        ((float4*)pose_s)[(srow * 4 + icol) * 4 + wd] = ((const float4*)pose)[gidx];
    } else if (tid < 160) {
        const int j = tid - 128;                  // 0..31
        const int srow = j >> 2, icol = j & 3;
        act_s[srow * 4 + icol] = act[(size_t)b * NN + (sg * 8 + srow) * 32 + iq * 4 + icol];
    }

    // ---- per-wave w load: 16 registers, once ----
    const int i = iq * 4 + wv;
    const float4* wp = (const float4*)(wmat + ((size_t)i * 64 + o) * 16);
    float4 w0 = wp[0], w1 = wp[1], w2 = wp[2], w3 = wp[3];

    // ---- stats prologue (recomputed per wave; deterministic) ----
    float m[16], i2v[16], zzb = 0.f;
    if (!FIRST) {
        const float* ac = accumPrev + (size_t)b * ACC_PER_B;
        float rps = ac[32 * 64 + o];
        float logsum = 0.f;
        #pragma unroll
        for (int p = 0; p < 16; p++) {
            float s1 = ac[p * 64 + o];
            float s2 = ac[(16 + p) * 64 + o];
            float mm = s1 / rps;
            float vv = fmaxf(s2 / rps - mm * mm, 0.f);
            m[p] = mm;
            i2v[p] = 0.5f / vv;
            logsum += __logf(sqrtf(vv) + EPSF);
        }
        float cost = rps * (16.0f * beta_v[o] + logsum);
        float cm = cost;
        #pragma unroll
        for (int s = 32; s > 0; s >>= 1) cm += __shfl_xor(cm, s, 64);
        cm *= (1.0f / 64.0f);
        float d = cost - cm;
        float cs = d * d;
        #pragma unroll
        for (int s = 32; s > 0; s >>= 1) cs += __shfl_xor(cs, s, 64);
        cs = sqrtf(cs * (1.0f / 64.0f));
        float x = inv_temp * (beta_a[o] + (cm - cost) / (cs + EPSF));
        float oa = 1.0f / (1.0f + __expf(-x));
        zzb = __logf(oa + EPSF) - logsum;
    }

    float accR = 0.f, acc1[16], acc2[16];
    #pragma unroll
    for (int p = 0; p < 16; p++) { acc1[p] = 0.f; acc2[p] = 0.f; }

    __syncthreads();

    // ---- site loop: LDS broadcast + VALU only ----
    for (int s = 0; s < 8; s++) {
        const int sp = sg * 8 + s;
        const float c0 = ((sp >> 3) + 0.5f) * 0.125f;
        const float c1 = ((sp & 7) + 0.5f) * 0.125f;
        const float* pr = pose_s + (s * 4 + wv) * 16;  // wave-uniform -> broadcast
        float v[16];
        #pragma unroll
        for (int a = 0; a < 4; a++) {
            float pa0 = pr[a * 4 + 0], pa1 = pr[a * 4 + 1];
            float pa2 = pr[a * 4 + 2], pa3 = pr[a * 4 + 3];
            v[a * 4 + 0] = pa0 * w0.x + pa1 * w1.x + pa2 * w2.x + pa3 * w3.x;
            v[a * 4 + 1] = pa0 * w0.y + pa1 * w1.y + pa2 * w2.y + pa3 * w3.y;
            v[a * 4 + 2] = pa0 * w0.z + pa1 * w1.z + pa2 * w2.z + pa3 * w3.z;
            v[a * 4 + 3] = pa0 * w0.w + pa1 * w1.w + pa2 * w2.w + pa3 * w3.w;
        }
        v[0] += c0;
        v[1] += c1;

        float rr;
        if (FIRST) {
            rr = 1.0f / 64.0f;
        } else {
            float d = zzb;
            #pragma unroll
            for (int p = 0; p < 16; p++) {
                float t = v[p] - m[p];
                d -= t * t * i2v[p];
            }
            float mx = d;
            #pragma unroll
            for (int sh = 32; sh > 0; sh >>= 1) mx = fmaxf(mx, __shfl_xor(mx, sh, 64));
            float e = __expf(d - mx);
            float sum = e;
            #pragma unroll
            for (int sh = 32; sh > 0; sh >>= 1) sum += __shfl_xor(sum, sh, 64);
            rr = e / sum;
        }
        float rp = rr * act_s[s * 4 + wv];
        accR += rp;
        #pragma unroll
        for (int p = 0; p < 16; p++) {
            float t = rp * v[p];
            acc1[p] += t;
            acc2[p] += t * v[p];
        }
    }

    float* ao = accumOut + (size_t)b * ACC_PER_B;
    atomicAdd(ao + 32 * 64 + o, accR);
    #pragma unroll
    for (int p = 0; p < 16; p++) atomicAdd(ao + p * 64 + o, acc1[p]);
    #pragma unroll
    for (int p = 0; p < 16; p++) atomicAdd(ao + (16 + p) * 64 + o, acc2[p]);
}

__global__ __launch_bounds__(64) void stats_final_kernel(
    const float* __restrict__ accum,   // [B][33][64]
    const float* __restrict__ beta_v,  // [64]
    const float* __restrict__ beta_a,  // [64]
    float* __restrict__ out,           // poses [B][64][16] then acts [B][64]
    float inv_temp)
{
    const int b = blockIdx.x;
    const int o = threadIdx.x;
    const float* ac = accum + (size_t)b * ACC_PER_B;

    float rps = ac[32 * 64 + o];
    float m[16];
    float logsum = 0.f;
    #pragma unroll
    for (int p = 0; p < 16; p++) {
        float s1 = ac[p * 64 + o];
        float s2 = ac[(16 + p) * 64 + o];
        float mm = s1 / rps;
        float vv = fmaxf(s2 / rps - mm * mm, 0.f);
        m[p] = mm;
        logsum += __logf(sqrtf(vv) + EPSF);
    }
    float cost = rps * (16.0f * beta_v[o] + logsum);

    float cm = cost;
    #pragma unroll
    for (int s = 32; s > 0; s >>= 1) cm += __shfl_xor(cm, s, 64);
    cm *= (1.0f / 64.0f);
    float d = cost - cm;
    float cs = d * d;
    #pragma unroll
    for (int s = 32; s > 0; s >>= 1) cs += __shfl_xor(cs, s, 64);
    cs = sqrtf(cs * (1.0f / 64.0f));

    float x = inv_temp * (beta_a[o] + (cm - cost) / (cs + EPSF));
    float oa = 1.0f / (1.0f + __expf(-x));

    float* op = out + ((size_t)b * 64 + o) * 16;
    #pragma unroll
    for (int p = 0; p < 16; p++) op[p] = m[p];
    out[(size_t)NB * NO * NP + (size_t)b * 64 + o] = oa;
}

extern "C" void kernel_launch(void* const* d_in, const int* in_sizes, int n_in,
                              void* d_out, int out_size, void* d_ws, size_t ws_size,
                              hipStream_t stream) {
    const float* pose   = (const float*)d_in[0];  // (32,8,8,32,4,4)
    const float* act    = (const float*)d_in[1];  // (32,8,8,32)
    const float* wmat   = (const float*)d_in[2];  // (32,64,4,4)
    const float* beta_v = (const float*)d_in[3];  // (1,64)
    const float* beta_a = (const float*)d_in[4];  // (1,64)
    float* out = (float*)d_out;
    float* ws = (float*)d_ws;

    float* accum0 = ws;
    float* accum1 = ws + ACC_TOTAL;
    float* accum2 = ws + 2 * (size_t)ACC_TOTAL;

    // zero the three atomic-accumulator regions (ws is poisoned every call)
    hipMemsetAsync(ws, 0, 3 * (size_t)ACC_TOTAL * sizeof(float), stream);

    dim3 grid(64, NB);  // (site-group x i-quad) x b = 2048 blocks
    accum_kernel<true><<<grid, 256, 0, stream>>>(
        pose, act, wmat, nullptr, beta_v, beta_a, 0.f, accum0);
    accum_kernel<false><<<grid, 256, 0, stream>>>(
        pose, act, wmat, accum0, beta_v, beta_a, 1.0f, accum1);
    accum_kernel<false><<<grid, 256, 0, stream>>>(
        pose, act, wmat, accum1, beta_v, beta_a, 2.0f, accum2);
    stats_final_kernel<<<NB, 64, 0, stream>>>(accum2, beta_v, beta_a, out, 3.0f);
}